// Round 2
// baseline (297.280 us; speedup 1.0000x reference)
//
#include <hip/hip_runtime.h>
#include <hip/hip_bf16.h>
#include <math.h>

typedef __attribute__((ext_vector_type(4))) float floatx4;
typedef __attribute__((ext_vector_type(8))) __bf16 bf16x8;

#define B_ROWS 4096
#define D_DIM  1024
#define C_CUR  1000
#define P_PREV 2000
#define C_PAD  1024
#define P_PAD  2048
#define N_TOT  (C_PAD + P_PAD)   // 3072

// ---------------------------------------------------------------------------
__global__ void zero_acc_kernel(float* __restrict__ acc) {
  if (threadIdx.x < 4) acc[threadIdx.x] = 0.f;
}

// ---------------------------------------------------------------------------
// Row L2-normalize (fp32 -> bf16), zero-fill padding rows.
// grid = total rows (incl. padding), block = 256. D_DIM = 1024 = 256*4.
// ---------------------------------------------------------------------------
__global__ __launch_bounds__(256) void norm_rows_kernel(
    const float* __restrict__ src, __hip_bfloat16* __restrict__ dst,
    int valid_rows) {
  const int r = blockIdx.x;
  const int t = threadIdx.x;
  unsigned short* drow = (unsigned short*)dst + (size_t)r * D_DIM;
  if (r >= valid_rows) {
    ushort4 z = {0, 0, 0, 0};
    *(ushort4*)(drow + t * 4) = z;
    return;
  }
  const float* row = src + (size_t)r * D_DIM;
  float4 v = *(const float4*)(row + t * 4);
  __shared__ float red[256];
  red[t] = v.x * v.x + v.y * v.y + v.z * v.z + v.w * v.w;
  __syncthreads();
  for (int o = 128; o > 0; o >>= 1) {
    if (t < o) red[t] += red[t + o];
    __syncthreads();
  }
  const float inv = 1.0f / fmaxf(sqrtf(red[0]), 1e-12f);
  __hip_bfloat16 h0 = __float2bfloat16(v.x * inv);
  __hip_bfloat16 h1 = __float2bfloat16(v.y * inv);
  __hip_bfloat16 h2 = __float2bfloat16(v.z * inv);
  __hip_bfloat16 h3 = __float2bfloat16(v.w * inv);
  ushort4 u;
  u.x = *(unsigned short*)&h0;
  u.y = *(unsigned short*)&h1;
  u.z = *(unsigned short*)&h2;
  u.w = *(unsigned short*)&h3;
  *(ushort4*)(drow + t * 4) = u;
}

// ---------------------------------------------------------------------------
// C[M][N] = A[M][K] * B[N][K]^T  (both row-major, contiguous K), bf16 in,
// bf16 out (fp32 accumulate). 128x128 block tile, BK=32, 4 waves in 2x2,
// each wave 4x4 frags of 16x16x32 MFMA.
// C/D mapping (verified, learn_hip m89/m91): row=(lane>>4)*4+reg, col=lane&15.
// A frag: A[m=lane&15][k=(lane>>4)*8+j]; B frag: Brow[n=lane&15][k=(lane>>4)*8+j].
// ---------------------------------------------------------------------------
#define TM   128
#define BK   32
#define LSTR 40   // shorts per LDS row: 32 + 8 pad (80B stride, 16B aligned)

__global__ __launch_bounds__(256) void gemm_bf16_kernel(
    const __hip_bfloat16* __restrict__ A,   // [B_ROWS][D_DIM]
    const __hip_bfloat16* __restrict__ Bm,  // [N_TOT][D_DIM]
    __hip_bfloat16* __restrict__ Cm) {      // [B_ROWS][N_TOT]
  __shared__ alignas(16) unsigned short lA[TM * LSTR];
  __shared__ alignas(16) unsigned short lB[TM * LSTR];
  const int t = threadIdx.x;
  const int bm = blockIdx.y, bn = blockIdx.x;
  const unsigned short* Ag = (const unsigned short*)A + (size_t)bm * TM * D_DIM;
  const unsigned short* Bg = (const unsigned short*)Bm + (size_t)bn * TM * D_DIM;

  const int lane = t & 63, wv = t >> 6;
  const int wm = (wv >> 1) * 64, wn = (wv & 1) * 64;
  const int quad = lane >> 4, l16 = lane & 15;

  // staging: 512 16B-chunks per tile, 2 per thread. chunk q -> row q>>2, k-off (q&3)*8
  const int q0 = t * 2, q1 = t * 2 + 1;
  const int ar0 = q0 >> 2, ak0 = (q0 & 3) * 8;
  const int ar1 = q1 >> 2, ak1 = (q1 & 3) * 8;

  floatx4 acc[4][4] = {};

  for (int kk = 0; kk < D_DIM; kk += BK) {
    float4 a0 = *(const float4*)(Ag + (size_t)ar0 * D_DIM + kk + ak0);
    float4 a1 = *(const float4*)(Ag + (size_t)ar1 * D_DIM + kk + ak1);
    float4 b0 = *(const float4*)(Bg + (size_t)ar0 * D_DIM + kk + ak0);
    float4 b1 = *(const float4*)(Bg + (size_t)ar1 * D_DIM + kk + ak1);
    __syncthreads();
    *(float4*)(lA + ar0 * LSTR + ak0) = a0;
    *(float4*)(lA + ar1 * LSTR + ak1) = a1;
    *(float4*)(lB + ar0 * LSTR + ak0) = b0;
    *(float4*)(lB + ar1 * LSTR + ak1) = b1;
    __syncthreads();
    bf16x8 af[4], bf[4];
#pragma unroll
    for (int i = 0; i < 4; ++i)
      af[i] = *(const bf16x8*)(lA + (wm + i * 16 + l16) * LSTR + quad * 8);
#pragma unroll
    for (int j = 0; j < 4; ++j)
      bf[j] = *(const bf16x8*)(lB + (wn + j * 16 + l16) * LSTR + quad * 8);
#pragma unroll
    for (int i = 0; i < 4; ++i)
#pragma unroll
      for (int j = 0; j < 4; ++j)
        acc[i][j] = __builtin_amdgcn_mfma_f32_16x16x32_bf16(af[i], bf[j], acc[i][j], 0, 0, 0);
  }

  unsigned short* Cu = (unsigned short*)Cm;
#pragma unroll
  for (int i = 0; i < 4; ++i)
#pragma unroll
    for (int j = 0; j < 4; ++j)
#pragma unroll
      for (int r = 0; r < 4; ++r) {
        const int row = bm * TM + wm + i * 16 + quad * 4 + r;
        const int col = bn * TM + wn + j * 16 + l16;
        __hip_bfloat16 h = __float2bfloat16(acc[i][j][r]);
        Cu[(size_t)row * N_TOT + col] = *(unsigned short*)&h;
      }
}

// ---------------------------------------------------------------------------
// Intra-domain: per row b over sims[b][0..C_CUR): std(ddof=1) -> temp ->
// infonce = logsumexp(s/temp) - s[label]/temp; also pos term 1 - s[label].
// ---------------------------------------------------------------------------
__global__ __launch_bounds__(256) void reduce_intra_kernel(
    const __hip_bfloat16* __restrict__ sims, const int* __restrict__ labels,
    float* __restrict__ acc) {
  const int b = blockIdx.x, t = threadIdx.x;
  const __hip_bfloat16* row = sims + (size_t)b * N_TOT;
  __shared__ float s1[256], s2[256], s3[256];
  float sum = 0.f, sumsq = 0.f, mx = -1e30f;
  for (int c = t; c < C_CUR; c += 256) {
    float v = __bfloat162float(row[c]);
    sum += v; sumsq += v * v; mx = fmaxf(mx, v);
  }
  s1[t] = sum; s2[t] = sumsq; s3[t] = mx;
  __syncthreads();
  for (int o = 128; o > 0; o >>= 1) {
    if (t < o) {
      s1[t] += s1[t + o];
      s2[t] += s2[t + o];
      s3[t] = fmaxf(s3[t], s3[t + o]);
    }
    __syncthreads();
  }
  sum = s1[0]; sumsq = s2[0]; mx = s3[0];
  const float var = (sumsq - sum * sum / (float)C_CUR) / (float)(C_CUR - 1);
  const float sd = sqrtf(fmaxf(var, 0.f));
  const float temp = fminf(fmaxf(0.07f * (1.f + sd), 0.01f), 0.5f);
  const float it = 1.f / temp;
  __syncthreads();
  float se = 0.f;
  for (int c = t; c < C_CUR; c += 256) {
    float v = __bfloat162float(row[c]);
    se += __expf((v - mx) * it);
  }
  s1[t] = se;
  __syncthreads();
  for (int o = 128; o > 0; o >>= 1) {
    if (t < o) s1[t] += s1[t + o];
    __syncthreads();
  }
  if (t == 0) {
    const float slab = __bfloat162float(row[labels[b]]);
    const float lse = mx * it + logf(s1[0]);
    atomicAdd(&acc[0], 1.f - slab);
    atomicAdd(&acc[1], lse - slab * it);
  }
}

// ---------------------------------------------------------------------------
// Cross-domain: per row b over sims[b][C_PAD..C_PAD+P_PREV) with mask
// (ppl[p] != labels[b]): masked mean/var(ddof=1) -> ctemp = 2*clip(...) ->
// cross = logsumexp(masked c/ctemp).
// ---------------------------------------------------------------------------
__global__ __launch_bounds__(256) void reduce_cross_kernel(
    const __hip_bfloat16* __restrict__ sims, const int* __restrict__ labels,
    const int* __restrict__ ppl, float* __restrict__ acc) {
  const int b = blockIdx.x, t = threadIdx.x;
  const __hip_bfloat16* row = sims + (size_t)b * N_TOT + C_PAD;
  const int lab = labels[b];
  __shared__ float s1[256], s2[256], s3[256], s4[256];
  float sum = 0.f, sumsq = 0.f, mx = -1e30f, cnt = 0.f;
  for (int p = t; p < P_PREV; p += 256) {
    if (ppl[p] != lab) {
      float v = __bfloat162float(row[p]);
      sum += v; sumsq += v * v; mx = fmaxf(mx, v); cnt += 1.f;
    }
  }
  s1[t] = sum; s2[t] = sumsq; s3[t] = mx; s4[t] = cnt;
  __syncthreads();
  for (int o = 128; o > 0; o >>= 1) {
    if (t < o) {
      s1[t] += s1[t + o];
      s2[t] += s2[t + o];
      s3[t] = fmaxf(s3[t], s3[t + o]);
      s4[t] += s4[t + o];
    }
    __syncthreads();
  }
  sum = s1[0]; sumsq = s2[0]; mx = s3[0];
  const float n = s4[0];
  const float var = (sumsq - sum * sum / n) / (n - 1.f);
  const float sd = sqrtf(fmaxf(var, 0.f));
  const float ct = 2.f * fminf(fmaxf(0.07f * (1.f + sd), 0.01f), 0.5f);
  const float it = 1.f / ct;
  __syncthreads();
  float se = 0.f;
  for (int p = t; p < P_PREV; p += 256) {
    if (ppl[p] != lab) {
      float v = __bfloat162float(row[p]);
      se += __expf((v - mx) * it);
    }
  }
  s1[t] = se;
  __syncthreads();
  for (int o = 128; o > 0; o >>= 1) {
    if (t < o) s1[t] += s1[t + o];
    __syncthreads();
  }
  if (t == 0) atomicAdd(&acc[2], mx * it + logf(s1[0]));
}

// ---------------------------------------------------------------------------
__global__ void finalize_kernel(const float* __restrict__ acc, float* __restrict__ out) {
  const float invB = 1.f / (float)B_ROWS;
  const float pos = acc[0] * invB;
  const float neg = acc[1] * invB + 0.3f * acc[2] * invB;
  const float curr_beta = 0.5f * (0.1f + 0.9f * (1.0f / 1000.0f));  // step=1, warmup=1000
  out[0] = 1.0f * pos + curr_beta * neg;                            // ALPHA=1
}

// ---------------------------------------------------------------------------
extern "C" void kernel_launch(void* const* d_in, const int* in_sizes, int n_in,
                              void* d_out, int out_size, void* d_ws, size_t ws_size,
                              hipStream_t stream) {
  const float* features   = (const float*)d_in[0];
  const float* cur_proto  = (const float*)d_in[1];
  const float* prev_proto = (const float*)d_in[2];
  const int*   labels     = (const int*)d_in[3];
  const int*   ppl        = (const int*)d_in[4];

  char* w = (char*)d_ws;
  __hip_bfloat16* fn    = (__hip_bfloat16*)w;                                  // 8 MB
  __hip_bfloat16* proto = (__hip_bfloat16*)(w + (size_t)8 * 1024 * 1024);      // 6 MB
  __hip_bfloat16* sims  = (__hip_bfloat16*)(w + (size_t)14 * 1024 * 1024);     // 24 MB
  float* acc = (float*)(w + (size_t)14 * 1024 * 1024 + (size_t)B_ROWS * N_TOT * 2);

  zero_acc_kernel<<<1, 64, 0, stream>>>(acc);

  norm_rows_kernel<<<B_ROWS, 256, 0, stream>>>(features, fn, B_ROWS);
  norm_rows_kernel<<<C_PAD, 256, 0, stream>>>(cur_proto, proto, C_CUR);
  norm_rows_kernel<<<P_PAD, 256, 0, stream>>>(prev_proto, proto + (size_t)C_PAD * D_DIM, P_PREV);

  dim3 grid(N_TOT / TM, B_ROWS / TM);
  gemm_bf16_kernel<<<grid, 256, 0, stream>>>(fn, proto, sims);

  reduce_intra_kernel<<<B_ROWS, 256, 0, stream>>>(sims, labels, acc);
  reduce_cross_kernel<<<B_ROWS, 256, 0, stream>>>(sims, labels, ppl, acc);
  finalize_kernel<<<1, 1, 0, stream>>>(acc, (float*)d_out);
}

// Round 3
// 162.002 us; speedup vs baseline: 1.8350x; 1.8350x over previous
//
#include <hip/hip_runtime.h>
#include <hip/hip_bf16.h>
#include <math.h>

typedef __attribute__((ext_vector_type(4))) float floatx4;
typedef __attribute__((ext_vector_type(8))) __bf16 bf16x8;

#define B_ROWS 4096
#define D_DIM  1024
#define C_CUR  1000
#define P_PREV 2000
#define C_PAD  1024
#define P_PAD  2048
#define N_TOT  (C_PAD + P_PAD)   // 3072

// ---------------------------------------------------------------------------
// Row L2-normalize (fp32 -> bf16), zero-fill padding rows.
// ---------------------------------------------------------------------------
__global__ __launch_bounds__(256) void norm_rows_kernel(
    const float* __restrict__ src, __hip_bfloat16* __restrict__ dst,
    int valid_rows) {
  const int r = blockIdx.x;
  const int t = threadIdx.x;
  unsigned short* drow = (unsigned short*)dst + (size_t)r * D_DIM;
  if (r >= valid_rows) {
    ushort4 z = {0, 0, 0, 0};
    *(ushort4*)(drow + t * 4) = z;
    return;
  }
  const float* row = src + (size_t)r * D_DIM;
  float4 v = *(const float4*)(row + t * 4);
  __shared__ float red[256];
  red[t] = v.x * v.x + v.y * v.y + v.z * v.z + v.w * v.w;
  __syncthreads();
  for (int o = 128; o > 0; o >>= 1) {
    if (t < o) red[t] += red[t + o];
    __syncthreads();
  }
  const float inv = 1.0f / fmaxf(sqrtf(red[0]), 1e-12f);
  __hip_bfloat16 h0 = __float2bfloat16(v.x * inv);
  __hip_bfloat16 h1 = __float2bfloat16(v.y * inv);
  __hip_bfloat16 h2 = __float2bfloat16(v.z * inv);
  __hip_bfloat16 h3 = __float2bfloat16(v.w * inv);
  ushort4 u;
  u.x = *(unsigned short*)&h0;
  u.y = *(unsigned short*)&h1;
  u.z = *(unsigned short*)&h2;
  u.w = *(unsigned short*)&h3;
  *(ushort4*)(drow + t * 4) = u;
}

// ---------------------------------------------------------------------------
// GEMM: C[M][N] = A[M][K] * B[N][K]^T, bf16 in/out, fp32 accum.
// 128x128 tile, BK=32, 4 waves 2x2, 4x4 frags of 16x16x32 MFMA.
// C/D mapping (verified m89/m91): row=(lane>>4)*4+reg, col=lane&15.
// ---------------------------------------------------------------------------
#define TM   128
#define BK   32
#define LSTR 40   // shorts per LDS row: 32 + 8 pad

__global__ __launch_bounds__(256) void gemm_bf16_kernel(
    const __hip_bfloat16* __restrict__ A,
    const __hip_bfloat16* __restrict__ Bm,
    __hip_bfloat16* __restrict__ Cm) {
  __shared__ alignas(16) unsigned short lA[TM * LSTR];
  __shared__ alignas(16) unsigned short lB[TM * LSTR];
  const int t = threadIdx.x;
  const int bm = blockIdx.y, bn = blockIdx.x;
  const unsigned short* Ag = (const unsigned short*)A + (size_t)bm * TM * D_DIM;
  const unsigned short* Bg = (const unsigned short*)Bm + (size_t)bn * TM * D_DIM;

  const int lane = t & 63, wv = t >> 6;
  const int wm = (wv >> 1) * 64, wn = (wv & 1) * 64;
  const int quad = lane >> 4, l16 = lane & 15;

  const int q0 = t * 2, q1 = t * 2 + 1;
  const int ar0 = q0 >> 2, ak0 = (q0 & 3) * 8;
  const int ar1 = q1 >> 2, ak1 = (q1 & 3) * 8;

  floatx4 acc[4][4] = {};

  for (int kk = 0; kk < D_DIM; kk += BK) {
    float4 a0 = *(const float4*)(Ag + (size_t)ar0 * D_DIM + kk + ak0);
    float4 a1 = *(const float4*)(Ag + (size_t)ar1 * D_DIM + kk + ak1);
    float4 b0 = *(const float4*)(Bg + (size_t)ar0 * D_DIM + kk + ak0);
    float4 b1 = *(const float4*)(Bg + (size_t)ar1 * D_DIM + kk + ak1);
    __syncthreads();
    *(float4*)(lA + ar0 * LSTR + ak0) = a0;
    *(float4*)(lA + ar1 * LSTR + ak1) = a1;
    *(float4*)(lB + ar0 * LSTR + ak0) = b0;
    *(float4*)(lB + ar1 * LSTR + ak1) = b1;
    __syncthreads();
    bf16x8 af[4], bf[4];
#pragma unroll
    for (int i = 0; i < 4; ++i)
      af[i] = *(const bf16x8*)(lA + (wm + i * 16 + l16) * LSTR + quad * 8);
#pragma unroll
    for (int j = 0; j < 4; ++j)
      bf[j] = *(const bf16x8*)(lB + (wn + j * 16 + l16) * LSTR + quad * 8);
#pragma unroll
    for (int i = 0; i < 4; ++i)
#pragma unroll
      for (int j = 0; j < 4; ++j)
        acc[i][j] = __builtin_amdgcn_mfma_f32_16x16x32_bf16(af[i], bf[j], acc[i][j], 0, 0, 0);
  }

  unsigned short* Cu = (unsigned short*)Cm;
#pragma unroll
  for (int i = 0; i < 4; ++i)
#pragma unroll
    for (int j = 0; j < 4; ++j)
#pragma unroll
      for (int r = 0; r < 4; ++r) {
        const int row = bm * TM + wm + i * 16 + quad * 4 + r;
        const int col = bn * TM + wn + j * 16 + l16;
        __hip_bfloat16 h = __float2bfloat16(acc[i][j][r]);
        Cu[(size_t)row * N_TOT + col] = *(unsigned short*)&h;
      }
}

// ---------------------------------------------------------------------------
// One WAVE per row b: intra InfoNCE + pos term + cross logsumexp.
// Shuffle-only reductions (no barriers, no atomics). 4 rows per block.
// Writes per-row partials; final_reduce combines.
// ---------------------------------------------------------------------------
__device__ __forceinline__ float wave_sum(float v) {
#pragma unroll
  for (int o = 32; o > 0; o >>= 1) v += __shfl_xor(v, o, 64);
  return v;
}
__device__ __forceinline__ float wave_max(float v) {
#pragma unroll
  for (int o = 32; o > 0; o >>= 1) v = fmaxf(v, __shfl_xor(v, o, 64));
  return v;
}

__global__ __launch_bounds__(256) void row_reduce_kernel(
    const __hip_bfloat16* __restrict__ sims, const int* __restrict__ labels,
    const int* __restrict__ ppl,
    float* __restrict__ pos_o, float* __restrict__ inf_o, float* __restrict__ crs_o) {
  const int wv = threadIdx.x >> 6, lane = threadIdx.x & 63;
  const int b = blockIdx.x * 4 + wv;
  const __hip_bfloat16* row = sims + (size_t)b * N_TOT;
  const int lab = labels[b];

  // ---- intra: cols [0, C_CUR) ----
  {
    float sum = 0.f, sumsq = 0.f, mx = -1e30f;
    for (int c = lane; c < C_CUR; c += 64) {
      float v = __bfloat162float(row[c]);
      sum += v; sumsq += v * v; mx = fmaxf(mx, v);
    }
    sum = wave_sum(sum); sumsq = wave_sum(sumsq); mx = wave_max(mx);
    const float var = (sumsq - sum * sum / (float)C_CUR) / (float)(C_CUR - 1);
    const float sd = sqrtf(fmaxf(var, 0.f));
    const float temp = fminf(fmaxf(0.07f * (1.f + sd), 0.01f), 0.5f);
    const float it = 1.f / temp;
    float se = 0.f;
    for (int c = lane; c < C_CUR; c += 64) {
      float v = __bfloat162float(row[c]);
      se += __expf((v - mx) * it);
    }
    se = wave_sum(se);
    if (lane == 0) {
      const float slab = __bfloat162float(row[lab]);
      pos_o[b] = 1.f - slab;
      inf_o[b] = mx * it + logf(se) - slab * it;
    }
  }

  // ---- cross: cols [C_PAD, C_PAD + P_PREV), masked by ppl != lab ----
  {
    const __hip_bfloat16* crow = row + C_PAD;
    float sum = 0.f, sumsq = 0.f, mx = -1e30f, cnt = 0.f;
    for (int p = lane; p < P_PREV; p += 64) {
      if (ppl[p] != lab) {
        float v = __bfloat162float(crow[p]);
        sum += v; sumsq += v * v; mx = fmaxf(mx, v); cnt += 1.f;
      }
    }
    sum = wave_sum(sum); sumsq = wave_sum(sumsq);
    mx = wave_max(mx); cnt = wave_sum(cnt);
    const float var = (sumsq - sum * sum / cnt) / (cnt - 1.f);
    const float sd = sqrtf(fmaxf(var, 0.f));
    const float ct = 2.f * fminf(fmaxf(0.07f * (1.f + sd), 0.01f), 0.5f);
    const float it = 1.f / ct;
    float se = 0.f;
    for (int p = lane; p < P_PREV; p += 64) {
      if (ppl[p] != lab) {
        float v = __bfloat162float(crow[p]);
        se += __expf((v - mx) * it);
      }
    }
    se = wave_sum(se);
    if (lane == 0) crs_o[b] = mx * it + logf(se);
  }
}

// ---------------------------------------------------------------------------
// Single block: combine 3x4096 per-row partials into the scalar loss.
// ---------------------------------------------------------------------------
__global__ __launch_bounds__(1024) void final_reduce_kernel(
    const float* __restrict__ pos_o, const float* __restrict__ inf_o,
    const float* __restrict__ crs_o, float* __restrict__ out) {
  const int t = threadIdx.x;
  __shared__ float sA[1024], sB[1024], sC[1024];
  float a = 0.f, bb = 0.f, c = 0.f;
  for (int i = t; i < B_ROWS; i += 1024) {
    a += pos_o[i]; bb += inf_o[i]; c += crs_o[i];
  }
  sA[t] = a; sB[t] = bb; sC[t] = c;
  __syncthreads();
  for (int o = 512; o > 0; o >>= 1) {
    if (t < o) { sA[t] += sA[t + o]; sB[t] += sB[t + o]; sC[t] += sC[t + o]; }
    __syncthreads();
  }
  if (t == 0) {
    const float invB = 1.f / (float)B_ROWS;
    const float pos = sA[0] * invB;
    const float neg = sB[0] * invB + 0.3f * sC[0] * invB;
    const float curr_beta = 0.5f * (0.1f + 0.9f * (1.0f / 1000.0f));  // step=1/warmup=1000
    out[0] = pos + curr_beta * neg;                                   // ALPHA=1
  }
}

// ---------------------------------------------------------------------------
extern "C" void kernel_launch(void* const* d_in, const int* in_sizes, int n_in,
                              void* d_out, int out_size, void* d_ws, size_t ws_size,
                              hipStream_t stream) {
  const float* features   = (const float*)d_in[0];
  const float* cur_proto  = (const float*)d_in[1];
  const float* prev_proto = (const float*)d_in[2];
  const int*   labels     = (const int*)d_in[3];
  const int*   ppl        = (const int*)d_in[4];

  char* w = (char*)d_ws;
  __hip_bfloat16* fn    = (__hip_bfloat16*)w;                                  // 8 MB
  __hip_bfloat16* proto = (__hip_bfloat16*)(w + (size_t)8 * 1024 * 1024);      // 6 MB
  __hip_bfloat16* sims  = (__hip_bfloat16*)(w + (size_t)14 * 1024 * 1024);     // 24 MB
  char* tail = w + (size_t)14 * 1024 * 1024 + (size_t)B_ROWS * N_TOT * 2;
  float* pos_o = (float*)tail;                 // 16 KB
  float* inf_o = pos_o + B_ROWS;               // 16 KB
  float* crs_o = inf_o + B_ROWS;               // 16 KB

  norm_rows_kernel<<<B_ROWS, 256, 0, stream>>>(features, fn, B_ROWS);
  norm_rows_kernel<<<C_PAD, 256, 0, stream>>>(cur_proto, proto, C_CUR);
  norm_rows_kernel<<<P_PAD, 256, 0, stream>>>(prev_proto, proto + (size_t)C_PAD * D_DIM, P_PREV);

  dim3 grid(N_TOT / TM, B_ROWS / TM);
  gemm_bf16_kernel<<<grid, 256, 0, stream>>>(fn, proto, sims);

  row_reduce_kernel<<<B_ROWS / 4, 256, 0, stream>>>(sims, labels, ppl, pos_o, inf_o, crs_o);
  final_reduce_kernel<<<1, 1024, 0, stream>>>(pos_o, inf_o, crs_o, (float*)d_out);
}

// Round 7
// 126.864 us; speedup vs baseline: 2.3433x; 1.2770x over previous
//
#include <hip/hip_runtime.h>
#include <hip/hip_bf16.h>
#include <math.h>

typedef __attribute__((ext_vector_type(4))) float floatx4;
typedef __attribute__((ext_vector_type(8))) __bf16 bf16x8;

#define B_ROWS 4096
#define D_DIM  1024
#define C_CUR  1000
#define P_PREV 2000
#define C_PAD  1024
#define P_PAD  2048
#define N_TOT  (C_PAD + P_PAD)   // 3072

__device__ __forceinline__ float wave_sum(float v) {
#pragma unroll
  for (int o = 32; o > 0; o >>= 1) v += __shfl_xor(v, o, 64);
  return v;
}
__device__ __forceinline__ float wave_max(float v) {
#pragma unroll
  for (int o = 32; o > 0; o >>= 1) v = fmaxf(v, __shfl_xor(v, o, 64));
  return v;
}

// ---------------------------------------------------------------------------
// Fused L2-normalize: one WAVE per row. rows 0..4095 = features -> fn,
// 4096..5119 = cur_proto -> proto[0..1024), 5120..7167 = prev_proto ->
// proto[1024..3072). Pad rows zero-filled. No LDS, no barriers.
// ---------------------------------------------------------------------------
__global__ __launch_bounds__(256) void norm_all_kernel(
    const float* __restrict__ features, const float* __restrict__ cur_proto,
    const float* __restrict__ prev_proto, __hip_bfloat16* __restrict__ fn,
    __hip_bfloat16* __restrict__ proto) {
  const int wv = threadIdx.x >> 6, lane = threadIdx.x & 63;
  const int r = blockIdx.x * 4 + wv;
  const float* src;
  unsigned short* dst;
  bool valid;
  if (r < B_ROWS) {
    src = features + (size_t)r * D_DIM;
    dst = (unsigned short*)fn + (size_t)r * D_DIM;
    valid = true;
  } else if (r < B_ROWS + C_PAD) {
    const int rr = r - B_ROWS;
    src = cur_proto + (size_t)rr * D_DIM;
    dst = (unsigned short*)proto + (size_t)rr * D_DIM;
    valid = rr < C_CUR;
  } else {
    const int rr = r - B_ROWS - C_PAD;
    src = prev_proto + (size_t)rr * D_DIM;
    dst = (unsigned short*)proto + (size_t)(C_PAD + rr) * D_DIM;
    valid = rr < P_PREV;
  }
  if (!valid) {
    ushort4 z = {0, 0, 0, 0};
#pragma unroll
    for (int k = 0; k < 4; ++k) *(ushort4*)(dst + lane * 4 + k * 256) = z;
    return;
  }
  float4 v[4];
  float ss = 0.f;
#pragma unroll
  for (int k = 0; k < 4; ++k) {
    v[k] = *(const float4*)(src + lane * 4 + k * 256);
    ss += v[k].x * v[k].x + v[k].y * v[k].y + v[k].z * v[k].z + v[k].w * v[k].w;
  }
  ss = wave_sum(ss);
  const float inv = 1.0f / fmaxf(sqrtf(ss), 1e-12f);
#pragma unroll
  for (int k = 0; k < 4; ++k) {
    __hip_bfloat16 h0 = __float2bfloat16(v[k].x * inv);
    __hip_bfloat16 h1 = __float2bfloat16(v[k].y * inv);
    __hip_bfloat16 h2 = __float2bfloat16(v[k].z * inv);
    __hip_bfloat16 h3 = __float2bfloat16(v[k].w * inv);
    ushort4 u;
    u.x = *(unsigned short*)&h0;
    u.y = *(unsigned short*)&h1;
    u.z = *(unsigned short*)&h2;
    u.w = *(unsigned short*)&h3;
    *(ushort4*)(dst + lane * 4 + k * 256) = u;
  }
}

// ---------------------------------------------------------------------------
// GEMM (R3-proven): C[M][N] = A[M][K]*B[N][K]^T, bf16 in/out, fp32 accum.
// 128x128 tile, BK=32, VGPR-roundtrip staging, padded LDS (LSTR=40).
// C/D mapping (m89/m91): row=(lane>>4)*4+reg, col=lane&15.
// NOTE: global_load_lds staging correlated with 3x container failures
// (R4-R6) -- reverted to this verbatim-R3 GEMM as the A/B control.
// ---------------------------------------------------------------------------
#define TM   128
#define BK   32
#define LSTR 40   // shorts per LDS row: 32 + 8 pad

__global__ __launch_bounds__(256) void gemm_bf16_kernel(
    const __hip_bfloat16* __restrict__ A,
    const __hip_bfloat16* __restrict__ Bm,
    __hip_bfloat16* __restrict__ Cm) {
  __shared__ alignas(16) unsigned short lA[TM * LSTR];
  __shared__ alignas(16) unsigned short lB[TM * LSTR];
  const int t = threadIdx.x;
  const int bm = blockIdx.y, bn = blockIdx.x;
  const unsigned short* Ag = (const unsigned short*)A + (size_t)bm * TM * D_DIM;
  const unsigned short* Bg = (const unsigned short*)Bm + (size_t)bn * TM * D_DIM;

  const int lane = t & 63, wv = t >> 6;
  const int wm = (wv >> 1) * 64, wn = (wv & 1) * 64;
  const int quad = lane >> 4, l16 = lane & 15;

  const int q0 = t * 2, q1 = t * 2 + 1;
  const int ar0 = q0 >> 2, ak0 = (q0 & 3) * 8;
  const int ar1 = q1 >> 2, ak1 = (q1 & 3) * 8;

  floatx4 acc[4][4] = {};

  for (int kk = 0; kk < D_DIM; kk += BK) {
    float4 a0 = *(const float4*)(Ag + (size_t)ar0 * D_DIM + kk + ak0);
    float4 a1 = *(const float4*)(Ag + (size_t)ar1 * D_DIM + kk + ak1);
    float4 b0 = *(const float4*)(Bg + (size_t)ar0 * D_DIM + kk + ak0);
    float4 b1 = *(const float4*)(Bg + (size_t)ar1 * D_DIM + kk + ak1);
    __syncthreads();
    *(float4*)(lA + ar0 * LSTR + ak0) = a0;
    *(float4*)(lA + ar1 * LSTR + ak1) = a1;
    *(float4*)(lB + ar0 * LSTR + ak0) = b0;
    *(float4*)(lB + ar1 * LSTR + ak1) = b1;
    __syncthreads();
    bf16x8 af[4], bfr[4];
#pragma unroll
    for (int i = 0; i < 4; ++i)
      af[i] = *(const bf16x8*)(lA + (wm + i * 16 + l16) * LSTR + quad * 8);
#pragma unroll
    for (int j = 0; j < 4; ++j)
      bfr[j] = *(const bf16x8*)(lB + (wn + j * 16 + l16) * LSTR + quad * 8);
#pragma unroll
    for (int i = 0; i < 4; ++i)
#pragma unroll
      for (int j = 0; j < 4; ++j)
        acc[i][j] = __builtin_amdgcn_mfma_f32_16x16x32_bf16(af[i], bfr[j], acc[i][j], 0, 0, 0);
  }

  unsigned short* Cu = (unsigned short*)Cm;
#pragma unroll
  for (int i = 0; i < 4; ++i)
#pragma unroll
    for (int j = 0; j < 4; ++j)
#pragma unroll
      for (int r = 0; r < 4; ++r) {
        const int row = bm * TM + wm + i * 16 + quad * 4 + r;
        const int col = bn * TM + wn + j * 16 + l16;
        __hip_bfloat16 h = __float2bfloat16(acc[i][j][r]);
        Cu[(size_t)row * N_TOT + col] = *(unsigned short*)&h;
      }
}

// ---------------------------------------------------------------------------
// One WAVE per row, single-pass: values held in registers (16 intra + 32
// cross floats/lane), bf16x8 loads, ppl mask as bitfield. No barriers.
// ---------------------------------------------------------------------------
__global__ __launch_bounds__(256) void row_reduce_kernel(
    const __hip_bfloat16* __restrict__ sims, const int* __restrict__ labels,
    const int* __restrict__ ppl,
    float* __restrict__ pos_o, float* __restrict__ inf_o, float* __restrict__ crs_o) {
  const int wv = threadIdx.x >> 6, lane = threadIdx.x & 63;
  const int b = blockIdx.x * 4 + wv;
  const unsigned short* row = (const unsigned short*)sims + (size_t)b * N_TOT;
  const int lab = labels[b];

  // ---- intra: cols [0, 1000); cols [1000,1024) are exact zeros (pad), masked
  {
    const int i0 = lane * 8, i1 = 512 + lane * 8;
    float vi[16];
    bf16x8 u0 = *(const bf16x8*)(row + i0);
    bf16x8 u1 = *(const bf16x8*)(row + i1);
#pragma unroll
    for (int j = 0; j < 8; ++j) { vi[j] = (float)u0[j]; vi[8 + j] = (float)u1[j]; }
    float sum = 0.f, sq = 0.f, mx = -1e30f;
#pragma unroll
    for (int j = 0; j < 8; ++j) {
      float v = vi[j];
      sum += v; sq += v * v; mx = fmaxf(mx, v);  // i0+j < 512 < 1000 always
    }
#pragma unroll
    for (int j = 0; j < 8; ++j) {
      if (i1 + j < C_CUR) { float v = vi[8 + j]; sum += v; sq += v * v; mx = fmaxf(mx, v); }
    }
    sum = wave_sum(sum); sq = wave_sum(sq); mx = wave_max(mx);
    const float var = (sq - sum * sum / (float)C_CUR) / (float)(C_CUR - 1);
    const float sd = sqrtf(fmaxf(var, 0.f));
    const float temp = fminf(fmaxf(0.07f * (1.f + sd), 0.01f), 0.5f);
    const float it = 1.f / temp;
    float se = 0.f;
#pragma unroll
    for (int j = 0; j < 8; ++j) se += __expf((vi[j] - mx) * it);
#pragma unroll
    for (int j = 0; j < 8; ++j)
      if (i1 + j < C_CUR) se += __expf((vi[8 + j] - mx) * it);
    se = wave_sum(se);
    if (lane == 0) {
      __hip_bfloat16 hs;
      *(unsigned short*)&hs = row[lab];
      const float slab = __bfloat162float(hs);
      pos_o[b] = 1.f - slab;
      inf_o[b] = mx * it + logf(se) - slab * it;
    }
  }

  // ---- cross: cols [1024, 3072) = prev protos 0..2047 (2000 valid + pad) ----
  {
    const unsigned short* crow = row + C_PAD;
    float vc[32];
    unsigned mask = 0;
    float sum = 0.f, sq = 0.f, mx = -1e30f;
    int cnt = 0;
#pragma unroll
    for (int k = 0; k < 4; ++k) {
      const int base = k * 512 + lane * 8;
      bf16x8 u = *(const bf16x8*)(crow + base);
#pragma unroll
      for (int j = 0; j < 8; ++j) vc[k * 8 + j] = (float)u[j];
      if (base < P_PREV) {  // base multiple of 8, so base<2000 => base+8<=2000
        int4 p0 = *(const int4*)(ppl + base);
        int4 p1 = *(const int4*)(ppl + base + 4);
        const int pl[8] = {p0.x, p0.y, p0.z, p0.w, p1.x, p1.y, p1.z, p1.w};
#pragma unroll
        for (int j = 0; j < 8; ++j) {
          if (pl[j] != lab) {
            mask |= 1u << (k * 8 + j);
            float v = vc[k * 8 + j];
            sum += v; sq += v * v; mx = fmaxf(mx, v); ++cnt;
          }
        }
      }
    }
    sum = wave_sum(sum); sq = wave_sum(sq); mx = wave_max(mx);
    const float n = wave_sum((float)cnt);
    const float var = (sq - sum * sum / n) / (n - 1.f);
    const float sd = sqrtf(fmaxf(var, 0.f));
    const float ct = 2.f * fminf(fmaxf(0.07f * (1.f + sd), 0.01f), 0.5f);
    const float it = 1.f / ct;
    float se = 0.f;
#pragma unroll
    for (int e = 0; e < 32; ++e)
      if ((mask >> e) & 1u) se += __expf((vc[e] - mx) * it);
    se = wave_sum(se);
    if (lane == 0) crs_o[b] = mx * it + logf(se);
  }
}

// ---------------------------------------------------------------------------
__global__ __launch_bounds__(1024) void final_reduce_kernel(
    const float* __restrict__ pos_o, const float* __restrict__ inf_o,
    const float* __restrict__ crs_o, float* __restrict__ out) {
  const int t = threadIdx.x;
  __shared__ float sA[1024], sB[1024], sC[1024];
  float a = 0.f, bb = 0.f, c = 0.f;
  for (int i = t; i < B_ROWS; i += 1024) {
    a += pos_o[i]; bb += inf_o[i]; c += crs_o[i];
  }
  sA[t] = a; sB[t] = bb; sC[t] = c;
  __syncthreads();
  for (int o = 512; o > 0; o >>= 1) {
    if (t < o) { sA[t] += sA[t + o]; sB[t] += sB[t + o]; sC[t] += sC[t + o]; }
    __syncthreads();
  }
  if (t == 0) {
    const float invB = 1.f / (float)B_ROWS;
    const float pos = sA[0] * invB;
    const float neg = sB[0] * invB + 0.3f * sC[0] * invB;
    const float curr_beta = 0.5f * (0.1f + 0.9f * (1.0f / 1000.0f));  // step=1/warmup=1000
    out[0] = pos + curr_beta * neg;                                   // ALPHA=1
  }
}

// ---------------------------------------------------------------------------
extern "C" void kernel_launch(void* const* d_in, const int* in_sizes, int n_in,
                              void* d_out, int out_size, void* d_ws, size_t ws_size,
                              hipStream_t stream) {
  const float* features   = (const float*)d_in[0];
  const float* cur_proto  = (const float*)d_in[1];
  const float* prev_proto = (const float*)d_in[2];
  const int*   labels     = (const int*)d_in[3];
  const int*   ppl        = (const int*)d_in[4];

  char* w = (char*)d_ws;
  __hip_bfloat16* fn    = (__hip_bfloat16*)w;                                  // 8 MB
  __hip_bfloat16* proto = (__hip_bfloat16*)(w + (size_t)8 * 1024 * 1024);      // 6 MB
  __hip_bfloat16* sims  = (__hip_bfloat16*)(w + (size_t)14 * 1024 * 1024);     // 24 MB
  char* tail = w + (size_t)14 * 1024 * 1024 + (size_t)B_ROWS * N_TOT * 2;
  float* pos_o = (float*)tail;
  float* inf_o = pos_o + B_ROWS;
  float* crs_o = inf_o + B_ROWS;

  norm_all_kernel<<<(B_ROWS + C_PAD + P_PAD) / 4, 256, 0, stream>>>(
      features, cur_proto, prev_proto, fn, proto);

  dim3 grid(N_TOT / TM, B_ROWS / TM);
  gemm_bf16_kernel<<<grid, 256, 0, stream>>>(fn, proto, sims);

  row_reduce_kernel<<<B_ROWS / 4, 256, 0, stream>>>(sims, labels, ppl, pos_o, inf_o, crs_o);
  final_reduce_kernel<<<1, 1024, 0, stream>>>(pos_o, inf_o, crs_o, (float*)d_out);
}